// Round 1
// baseline (268.677 us; speedup 1.0000x reference)
//
#include <hip/hip_runtime.h>

// VQ-VAE vector quantizer — R7.
// R6 post-mortem: vq_argmin latency/structure-bound (VALU 37%, MFMA 12.5%,
// HBM 8%, 1.58M LDS bank conflicts); ~70us of the 153.6us total lives OUTSIDE
// vq_argmin (3 epilogue kernels + 4 serialized launches).
// R7 changes:
//  1. A-fragments loaded DIRECTLY from global in fragment order (lane ->
//     row w*16+ln15, ch quad*8+j): no LDS A-staging, no stage barriers,
//     no offA addressing, no bank conflicts. znrow via 2x shfl_xor.
//  2. ||e||^2 baked into MFMA accumulator init (C-in = env); branchless top-2.
//  3. vq_hist + vq_final FUSED into vq_argmin: per-block global-atomic
//     histogram from biarr, f64 agent-atomic SSE, last-block ticket computes
//     loss+perplexity. 4 kernels -> 2. vq_init zeroes accumulators per replay.

#define B_ 32
#define C_ 64
#define HW_ 4096
#define K_ 512
#define N_ (B_ * HW_)
#define NC_ ((long long)N_ * C_)
#define ROWS_ 64
#define NBLK_ (N_ / ROWS_)     // 2048

typedef __attribute__((ext_vector_type(8))) short short8;
typedef __attribute__((ext_vector_type(4))) float float4_t;

// ---- workspace layout (bytes) ----
// 0       int    done                last-block ticket
// 8       double ssed                global SSE accumulator
// 56      float  snmax               4*max_k ||e_k||^2
// 2112    float  en[512]
// 4160    float  embT32[512*64]      exact fp32 emb, [code][c]
// 135232  ushort fBhi[512*64]        bf16 hi of (-2e), fragment-linear
// 200768  ushort fBlo[512*64]        bf16 lo of (-2e), fragment-linear
// 266304  int    ghist[512]          global histogram

__device__ __forceinline__ unsigned short f2bf(float f) {
    unsigned u = __float_as_uint(f);
    u += 0x7fffu + ((u >> 16) & 1u);   // RNE
    return (unsigned short)(u >> 16);
}
__device__ __forceinline__ float bf2f(unsigned short h) {
    return __uint_as_float(((unsigned)h) << 16);
}
__device__ __forceinline__ void merge2(float& m1, int& i1, float& m2,
                                       float om1, int oi1, float om2) {
    if (om1 < m1) { m2 = fminf(m1, om2); m1 = om1; i1 = oi1; }
    else          { m2 = fminf(m2, om1); }
}

// ---------------- prologue ----------------
__global__ __launch_bounds__(512) void vq_init(const float* __restrict__ emb,
                                               float* __restrict__ snmax_p,
                                               float* __restrict__ en,
                                               float* __restrict__ embT32,
                                               unsigned short* __restrict__ fBhi,
                                               unsigned short* __restrict__ fBlo,
                                               int* __restrict__ ghist,
                                               int* __restrict__ done_p,
                                               double* __restrict__ ssed_p) {
    __shared__ float smax[8];
    int k = threadIdx.x;                  // code 0..511
    if (blockIdx.x < 64) {
        int c = blockIdx.x;
        float e = emb[c * K_ + k];        // coalesced over k
        embT32[k * C_ + c] = e;
        float s = -2.0f * e;
        unsigned short hi = f2bf(s);
        unsigned short lo = f2bf(s - bf2f(hi));
        // fragment-linear: fb = [k>>5][(k>>4)&1][c>>5], then lane, then 8 k
        int kk   = c >> 5;
        int lane = (((c & 31) >> 3) << 4) + (k & 15);
        int fb   = ((k >> 5) << 2) + (((k >> 4) & 1) << 1) + kk;
        int off  = (fb << 9) + (lane << 3) + (c & 7);
        fBhi[off] = hi;
        fBlo[off] = lo;
    } else {
        // zero the fused-epilogue accumulators (re-done every graph replay)
        ghist[k] = 0;
        if (k == 0) { *done_p = 0; *ssed_p = 0.0; }
        float s = 0.f;
#pragma unroll
        for (int c = 0; c < C_; ++c) {
            float e = emb[c * K_ + k];
            s += e * e;
        }
        en[k] = s;
        float m = s;
#pragma unroll
        for (int off = 32; off > 0; off >>= 1)
            m = fmaxf(m, __shfl_down(m, off, 64));
        if ((k & 63) == 0) smax[k >> 6] = m;
        __syncthreads();
        if (k == 0) {
            float mm = smax[0];
#pragma unroll
            for (int w2 = 1; w2 < 8; ++w2) mm = fmaxf(mm, smax[w2]);
            *snmax_p = 4.0f * mm;
        }
    }
}

// ---------------- main kernel: argmin + q + SSE + hist + final ----------------
__global__ __launch_bounds__(256) void vq_argmin(const float* __restrict__ x,
                                                 const float* __restrict__ en_g,
                                                 const float* __restrict__ embT32,
                                                 const unsigned short* __restrict__ fBhi,
                                                 const unsigned short* __restrict__ fBlo,
                                                 const float* __restrict__ snmax_p,
                                                 float* __restrict__ out_q,
                                                 float* __restrict__ out_idx,
                                                 int* __restrict__ ghist,
                                                 double* __restrict__ ssed_p,
                                                 int* __restrict__ done_p,
                                                 float* __restrict__ out_loss,
                                                 float* __restrict__ out_perp) {
    __shared__ float sEn[K_];                    // 2 KB
    __shared__ float znrow[ROWS_];
    __shared__ int   biarr[ROWS_];
    __shared__ int   flaglist[ROWS_];
    __shared__ float wsse[4];
    __shared__ int   nflag;
    __shared__ int   amLast;

    const int t    = threadIdx.x;
    const int lane = t & 63;
    const int w    = t >> 6;             // wave owns row-tile w (rows w*16..+15)
    const int ln15 = lane & 15;
    const int quad = lane >> 4;
    const int n0   = blockIdx.x * ROWS_;
    const int b    = n0 >> 12;
    const int hw0  = n0 & 4095;
    const float* xbase = x + ((size_t)b << 18) + hw0;
    const int myrow = (w << 4) + ln15;

    if (t == 0) nflag = 0;
    sEn[t]       = en_g[t];
    sEn[256 + t] = en_g[256 + t];

    // ---- direct A-fragment load: lane holds row=myrow, c = quad*8+j (+32) ----
    // 16-lane groups (ln15) give 64B contiguous segments per channel.
    float v0[8], v1[8];
#pragma unroll
    for (int j = 0; j < 8; ++j) {
        v0[j] = xbase[((size_t)((quad << 3) + j) << 12) + myrow];
        v1[j] = xbase[((size_t)(32 + (quad << 3) + j) << 12) + myrow];
    }
    short8 ah0, al0, ah1, al1;
    float znacc = 0.f;
#pragma unroll
    for (int j = 0; j < 8; ++j) {
        unsigned short h0 = f2bf(v0[j]);
        ah0[j] = (short)h0;
        al0[j] = (short)f2bf(v0[j] - bf2f(h0));
        unsigned short h1 = f2bf(v1[j]);
        ah1[j] = (short)h1;
        al1[j] = (short)f2bf(v1[j] - bf2f(h1));
        znacc += v0[j] * v0[j] + v1[j] * v1[j];
    }
    // full ||z_row||^2: reduce over the 4 quads holding the same row
    znacc += __shfl_xor(znacc, 16, 64);
    znacc += __shfl_xor(znacc, 32, 64);
    if (quad == 0) znrow[myrow] = znacc;
    __syncthreads();     // sEn + znrow + nflag visible

    const float snm = *snmax_p;

    // ---- stream 512 codes: 16 passes x 2 col-tiles; per-row branchless top-2 ----
    float m1[4], m2[4];
    int   i1[4];
#pragma unroll
    for (int reg = 0; reg < 4; ++reg) {
        m1[reg] = 3.4e38f; m2[reg] = 3.4e38f; i1[reg] = 0;
    }

    for (int p = 0; p < 16; ++p) {
#pragma unroll
        for (int ct = 0; ct < 2; ++ct) {
            const int cbase = (p << 5) + (ct << 4);
            const int fbase = ((((p << 2) + (ct << 1)) << 9) + (lane << 3));
            short8 bh0 = *(const short8*)(fBhi + fbase);        // 1 KB/instr, L2-hot
            short8 bh1 = *(const short8*)(fBhi + fbase + 512);
            short8 bl0 = *(const short8*)(fBlo + fbase);
            short8 bl1 = *(const short8*)(fBlo + fbase + 512);
            float env = sEn[cbase + ln15];
            int   idx = cbase + ln15;
            // env baked into C-in (per-column constant; D reg-dim is rows)
            float4_t a0 = {env, env, env, env};
            float4_t a1 = {0.f, 0.f, 0.f, 0.f};
            a0 = __builtin_amdgcn_mfma_f32_16x16x32_bf16(al0, bh0, a0, 0, 0, 0);
            a1 = __builtin_amdgcn_mfma_f32_16x16x32_bf16(al1, bh1, a1, 0, 0, 0);
            a0 = __builtin_amdgcn_mfma_f32_16x16x32_bf16(ah0, bl0, a0, 0, 0, 0);
            a1 = __builtin_amdgcn_mfma_f32_16x16x32_bf16(ah1, bl1, a1, 0, 0, 0);
            a0 = __builtin_amdgcn_mfma_f32_16x16x32_bf16(ah0, bh0, a0, 0, 0, 0);
            a1 = __builtin_amdgcn_mfma_f32_16x16x32_bf16(ah1, bh1, a1, 0, 0, 0);
#pragma unroll
            for (int reg = 0; reg < 4; ++reg) {
                float vv = a0[reg] + a1[reg];
                bool  lt = vv < m1[reg];
                float mx = fmaxf(vv, m1[reg]);       // top-2 identity:
                m2[reg] = fminf(m2[reg], mx);        //  m2' = min(m2, max(m1,vv))
                m1[reg] = fminf(m1[reg], vv);        //  m1' = min(m1, vv)
                i1[reg] = lt ? idx : i1[reg];
            }
        }
    }

    // ---- 16-lane butterfly finalize + flag decision ----
#pragma unroll
    for (int reg = 0; reg < 4; ++reg) {
        float a1v = m1[reg], a2v = m2[reg];
        int   ai  = i1[reg];
#pragma unroll
        for (int s = 1; s < 16; s <<= 1) {
            float o1 = __shfl_xor(a1v, s, 16);
            int   oi = __shfl_xor(ai, s, 16);
            float o2 = __shfl_xor(a2v, s, 16);
            merge2(a1v, ai, a2v, o1, oi, o2);
        }
        if (ln15 == 0) {
            int row = (w << 4) + (quad << 2) + reg;
            float znr = znrow[row];
            float W = 1.4e-4f * __builtin_sqrtf(znr * snm) + 1e-3f;  // sound 2x err bound
            biarr[row] = ai;
            if (a2v > a1v + W) {          // gap > W => approx argmin == exact argmin
                out_idx[n0 + row] = (float)ai;
            } else {
                int pos = atomicAdd(&nflag, 1);   // LDS atomic
                flaglist[pos] = row;
            }
        }
    }
    __syncthreads();

    // ---- exact fp32 rescue (one wave per flagged row; ~1% of rows) ----
    int nf = nflag;
    for (int f = w; f < nf; f += 4) {
        int r = flaglist[f];
        float zl = xbase[((size_t)lane << 12) + r];   // exact z[lane], L2-hot
        float d[8];
#pragma unroll
        for (int j = 0; j < 8; ++j) d[j] = 0.f;
        for (int c4 = 0; c4 < 16; ++c4) {
            float z0 = __shfl(zl, (c4 << 2) + 0, 64);
            float z1 = __shfl(zl, (c4 << 2) + 1, 64);
            float z2 = __shfl(zl, (c4 << 2) + 2, 64);
            float z3 = __shfl(zl, (c4 << 2) + 3, 64);
#pragma unroll
            for (int j = 0; j < 8; ++j) {
                float4_t e = *(const float4_t*)(embT32 + ((((lane << 3) + j) << 6) + (c4 << 2)));
                d[j] = fmaf(z0, e[0], d[j]);
                d[j] = fmaf(z1, e[1], d[j]);
                d[j] = fmaf(z2, e[2], d[j]);
                d[j] = fmaf(z3, e[3], d[j]);
            }
        }
        float znr = znrow[r];
        float best = 3.4e38f;
        int   bidx = 0;
#pragma unroll
        for (int j = 0; j < 8; ++j) {
            int k = (lane << 3) + j;
            float dist = (znr + sEn[k]) - 2.f * d[j];   // reference eval order
            if (dist < best) { best = dist; bidx = k; }
        }
#pragma unroll
        for (int off = 32; off > 0; off >>= 1) {
            float ov = __shfl_down(best, off, 64);
            int   oi = __shfl_down(bidx, off, 64);
            if (ov < best || (ov == best && oi < bidx)) { best = ov; bidx = oi; }
        }
        if (lane == 0) {
            biarr[r] = bidx;
            out_idx[n0 + r] = (float)bidx;
        }
    }
    __syncthreads();

    // ---- phase 2 (register-based): lane covers row = myrow, c = quad*8+j (+32) ----
    const int code  = biarr[myrow];
    const float* eb = embT32 + (code << 6) + (quad << 3);
    float4_t e0 = *(const float4_t*)(eb);          // c = quad*8 + 0..3
    float4_t e1 = *(const float4_t*)(eb + 4);      // c = quad*8 + 4..7
    float4_t e2 = *(const float4_t*)(eb + 32);     // c = 32 + quad*8 + 0..3
    float4_t e3 = *(const float4_t*)(eb + 36);     // c = 32 + quad*8 + 4..7
    float* qrow = out_q + ((size_t)b << 18) + hw0 + myrow;
    float sacc = 0.f;
#pragma unroll
    for (int j = 0; j < 4; ++j) {
        int c0 = (quad << 3) + j;
        int c1 = (quad << 3) + 4 + j;
        // chunk 0 (c < 32): frags ah0/al0
        float zA = bf2f((unsigned short)ah0[j])     + bf2f((unsigned short)al0[j]);
        float zB = bf2f((unsigned short)ah0[4 + j]) + bf2f((unsigned short)al0[4 + j]);
        float dA = e0[j] - zA, dB = e1[j] - zB;
        sacc += dA * dA + dB * dB;
        qrow[(size_t)c0 << 12] = e0[j];
        qrow[(size_t)c1 << 12] = e1[j];
        // chunk 1 (c >= 32): frags ah1/al1
        float zC = bf2f((unsigned short)ah1[j])     + bf2f((unsigned short)al1[j]);
        float zD = bf2f((unsigned short)ah1[4 + j]) + bf2f((unsigned short)al1[4 + j]);
        float dC = e2[j] - zC, dD = e3[j] - zD;
        sacc += dC * dC + dD * dD;
        qrow[(size_t)(32 + c0) << 12] = e2[j];
        qrow[(size_t)(32 + c1) << 12] = e3[j];
    }
#pragma unroll
    for (int off = 32; off > 0; off >>= 1)
        sacc += __shfl_down(sacc, off, 64);
    if (lane == 0) wsse[w] = sacc;

    // ---- fused histogram: 64 device-scope atomics per block ----
    if (t < ROWS_) atomicAdd(&ghist[biarr[t]], 1);
    __syncthreads();     // wsse written; all block atomics drained (vmcnt before barrier)

    // ---- last-block ticket -> loss + perplexity ----
    if (t == 0) {
        double bsum = (double)wsse[0] + (double)wsse[1]
                    + (double)wsse[2] + (double)wsse[3];
        __hip_atomic_fetch_add(ssed_p, bsum, __ATOMIC_RELAXED, __HIP_MEMORY_SCOPE_AGENT);
        __threadfence();
        amLast = (atomicAdd(done_p, 1) == NBLK_ - 1);
    }
    __syncthreads();
    if (amLast) {
        float s = 0.f;
        for (int kk = t; kk < K_; kk += 256) {
            int h = __hip_atomic_load(&ghist[kk], __ATOMIC_RELAXED, __HIP_MEMORY_SCOPE_AGENT);
            float pp = (float)h * (1.0f / (float)N_);
            s += pp * logf(pp + 1e-10f);
        }
#pragma unroll
        for (int off = 32; off > 0; off >>= 1)
            s += __shfl_down(s, off, 64);
        if (lane == 0) wsse[w] = s;   // safe: prior wsse use is before the barrier above
        __syncthreads();
        if (t == 0) {
            float S = wsse[0] + wsse[1] + wsse[2] + wsse[3];
            double D = __hip_atomic_load(ssed_p, __ATOMIC_RELAXED, __HIP_MEMORY_SCOPE_AGENT);
            *out_perp = expf(-S);
            *out_loss = (float)(1.25 * D / (double)NC_);
        }
    }
}

extern "C" void kernel_launch(void* const* d_in, const int* in_sizes, int n_in,
                              void* d_out, int out_size, void* d_ws, size_t ws_size,
                              hipStream_t stream) {
    const float* x   = (const float*)d_in[0];
    const float* emb = (const float*)d_in[1];

    float* out      = (float*)d_out;
    float* out_loss = out;
    float* out_q    = out + 1;
    float* out_perp = out + 1 + (size_t)N_ * C_;
    float* out_idx  = out + 2 + (size_t)N_ * C_;

    char* ws = (char*)d_ws;
    int*            done_p   = (int*)(ws + 0);
    double*         ssed_p   = (double*)(ws + 8);
    float*          snmax_p  = (float*)(ws + 56);
    float*          en       = (float*)(ws + 2112);
    float*          embT32   = (float*)(ws + 4160);
    unsigned short* fBhi     = (unsigned short*)(ws + 135232);
    unsigned short* fBlo     = (unsigned short*)(ws + 200768);
    int*            ghist    = (int*)(ws + 266304);

    vq_init<<<65, 512, 0, stream>>>(emb, snmax_p, en, embT32, fBhi, fBlo,
                                    ghist, done_p, ssed_p);
    vq_argmin<<<NBLK_, 256, 0, stream>>>(x, en, embT32, fBhi, fBlo, snmax_p,
                                         out_q, out_idx, ghist, ssed_p, done_p,
                                         out_loss, out_perp);
}

// Round 2
// 164.719 us; speedup vs baseline: 1.6311x; 1.6311x over previous
//
#include <hip/hip_runtime.h>

// VQ-VAE vector quantizer — R8.
// R7 post-mortem: fused epilogue regressed 83->210us. MFMA/VALU busy-TIME was
// unchanged (10.2/27us) => pure stall. Cause: per-block __threadfence (= L2
// writeback buffer_wbl2 x2048), contested device atomics (WRITE_SIZE +11MB =
// memory-side atomic traffic), and per-block barriers waiting on atomic ACKs.
// R8: keep R7's wins (direct fragment A-load: bank conflicts 1.58M->5K, no
// staging barriers; branchless top-2; ||e||^2 in MFMA C-in). Revert epilogue:
//  - NO fence, NO last-block ticket, NO f64 global atomic.
//  - SSE via ssepart[block] regular stores (R6-proven).
//  - histogram fused as relaxed no-return atomics into 8 slot copies, issued
//    AFTER the final barrier (ACK wait overlaps wave retire).
//  - tiny vq_final (1 block) does loss+perplexity; kernel boundary = the one
//    cross-XCD flush. 3 launches total.

#define B_ 32
#define C_ 64
#define HW_ 4096
#define K_ 512
#define N_ (B_ * HW_)
#define NC_ ((long long)N_ * C_)
#define ROWS_ 64
#define NBLK_ (N_ / ROWS_)     // 2048
#define NSLOT_ 8

typedef __attribute__((ext_vector_type(8))) short short8;
typedef __attribute__((ext_vector_type(4))) float float4_t;

// ---- workspace layout (bytes) ----
// 56      float  snmax               4*max_k ||e_k||^2
// 2112    float  en[512]
// 4160    float  embT32[512*64]      exact fp32 emb, [code][c]
// 135232  ushort fBhi[512*64]        bf16 hi of (-2e), fragment-linear
// 200768  ushort fBlo[512*64]        bf16 lo of (-2e), fragment-linear
// 266304  int    ghist8[8*512]       slotted histogram (16 KB)
// 282688  double ssepart[2048]       (16 KB) -> end 299072

__device__ __forceinline__ unsigned short f2bf(float f) {
    unsigned u = __float_as_uint(f);
    u += 0x7fffu + ((u >> 16) & 1u);   // RNE
    return (unsigned short)(u >> 16);
}
__device__ __forceinline__ float bf2f(unsigned short h) {
    return __uint_as_float(((unsigned)h) << 16);
}
__device__ __forceinline__ void merge2(float& m1, int& i1, float& m2,
                                       float om1, int oi1, float om2) {
    if (om1 < m1) { m2 = fminf(m1, om2); m1 = om1; i1 = oi1; }
    else          { m2 = fminf(m2, om1); }
}

// ---------------- prologue ----------------
__global__ __launch_bounds__(512) void vq_init(const float* __restrict__ emb,
                                               float* __restrict__ snmax_p,
                                               float* __restrict__ en,
                                               float* __restrict__ embT32,
                                               unsigned short* __restrict__ fBhi,
                                               unsigned short* __restrict__ fBlo,
                                               int* __restrict__ ghist8) {
    __shared__ float smax[8];
    int k = threadIdx.x;                  // code 0..511
    if (blockIdx.x < 64) {
        int c = blockIdx.x;
        float e = emb[c * K_ + k];        // coalesced over k
        embT32[k * C_ + c] = e;
        float s = -2.0f * e;
        unsigned short hi = f2bf(s);
        unsigned short lo = f2bf(s - bf2f(hi));
        // fragment-linear: fb = [k>>5][(k>>4)&1][c>>5], then lane, then 8 k
        int kk   = c >> 5;
        int lane = (((c & 31) >> 3) << 4) + (k & 15);
        int fb   = ((k >> 5) << 2) + (((k >> 4) & 1) << 1) + kk;
        int off  = (fb << 9) + (lane << 3) + (c & 7);
        fBhi[off] = hi;
        fBlo[off] = lo;
    } else {
        // zero slotted histogram (re-done every graph replay)
#pragma unroll
        for (int s8 = 0; s8 < NSLOT_; ++s8) ghist8[(s8 << 9) + k] = 0;
        float s = 0.f;
#pragma unroll
        for (int c = 0; c < C_; ++c) {
            float e = emb[c * K_ + k];
            s += e * e;
        }
        en[k] = s;
        float m = s;
#pragma unroll
        for (int off = 32; off > 0; off >>= 1)
            m = fmaxf(m, __shfl_down(m, off, 64));
        if ((k & 63) == 0) smax[k >> 6] = m;
        __syncthreads();
        if (k == 0) {
            float mm = smax[0];
#pragma unroll
            for (int w2 = 1; w2 < 8; ++w2) mm = fmaxf(mm, smax[w2]);
            *snmax_p = 4.0f * mm;
        }
    }
}

// ---------------- main kernel: argmin + q + SSE + slotted hist ----------------
__global__ __launch_bounds__(256) void vq_argmin(const float* __restrict__ x,
                                                 const float* __restrict__ en_g,
                                                 const float* __restrict__ embT32,
                                                 const unsigned short* __restrict__ fBhi,
                                                 const unsigned short* __restrict__ fBlo,
                                                 const float* __restrict__ snmax_p,
                                                 float* __restrict__ out_q,
                                                 float* __restrict__ out_idx,
                                                 int* __restrict__ ghist8,
                                                 double* __restrict__ ssepart) {
    __shared__ float sEn[K_];                    // 2 KB
    __shared__ float znrow[ROWS_];
    __shared__ int   biarr[ROWS_];
    __shared__ int   flaglist[ROWS_];
    __shared__ float wsse[4];
    __shared__ int   nflag;

    const int t    = threadIdx.x;
    const int lane = t & 63;
    const int w    = t >> 6;             // wave owns row-tile w (rows w*16..+15)
    const int ln15 = lane & 15;
    const int quad = lane >> 4;
    const int n0   = blockIdx.x * ROWS_;
    const int b    = n0 >> 12;
    const int hw0  = n0 & 4095;
    const float* xbase = x + ((size_t)b << 18) + hw0;
    const int myrow = (w << 4) + ln15;

    if (t == 0) nflag = 0;
    sEn[t]       = en_g[t];
    sEn[256 + t] = en_g[256 + t];

    // ---- direct A-fragment load: lane holds row=myrow, c = quad*8+j (+32) ----
    // 16-lane groups (ln15) give 64B contiguous segments per channel.
    float v0[8], v1[8];
#pragma unroll
    for (int j = 0; j < 8; ++j) {
        v0[j] = xbase[((size_t)((quad << 3) + j) << 12) + myrow];
        v1[j] = xbase[((size_t)(32 + (quad << 3) + j) << 12) + myrow];
    }
    short8 ah0, al0, ah1, al1;
    float znacc = 0.f;
#pragma unroll
    for (int j = 0; j < 8; ++j) {
        unsigned short h0 = f2bf(v0[j]);
        ah0[j] = (short)h0;
        al0[j] = (short)f2bf(v0[j] - bf2f(h0));
        unsigned short h1 = f2bf(v1[j]);
        ah1[j] = (short)h1;
        al1[j] = (short)f2bf(v1[j] - bf2f(h1));
        znacc += v0[j] * v0[j] + v1[j] * v1[j];
    }
    // full ||z_row||^2: reduce over the 4 quads holding the same row
    znacc += __shfl_xor(znacc, 16, 64);
    znacc += __shfl_xor(znacc, 32, 64);
    if (quad == 0) znrow[myrow] = znacc;
    __syncthreads();     // sEn + znrow + nflag visible

    const float snm = *snmax_p;

    // ---- stream 512 codes: 16 passes x 2 col-tiles; per-row branchless top-2 ----
    float m1[4], m2[4];
    int   i1[4];
#pragma unroll
    for (int reg = 0; reg < 4; ++reg) {
        m1[reg] = 3.4e38f; m2[reg] = 3.4e38f; i1[reg] = 0;
    }

    for (int p = 0; p < 16; ++p) {
#pragma unroll
        for (int ct = 0; ct < 2; ++ct) {
            const int cbase = (p << 5) + (ct << 4);
            const int fbase = ((((p << 2) + (ct << 1)) << 9) + (lane << 3));
            short8 bh0 = *(const short8*)(fBhi + fbase);        // 1 KB/instr, L2-hot
            short8 bh1 = *(const short8*)(fBhi + fbase + 512);
            short8 bl0 = *(const short8*)(fBlo + fbase);
            short8 bl1 = *(const short8*)(fBlo + fbase + 512);
            float env = sEn[cbase + ln15];
            int   idx = cbase + ln15;
            // env baked into C-in (per-column constant; D reg-dim is rows)
            float4_t a0 = {env, env, env, env};
            float4_t a1 = {0.f, 0.f, 0.f, 0.f};
            a0 = __builtin_amdgcn_mfma_f32_16x16x32_bf16(al0, bh0, a0, 0, 0, 0);
            a1 = __builtin_amdgcn_mfma_f32_16x16x32_bf16(al1, bh1, a1, 0, 0, 0);
            a0 = __builtin_amdgcn_mfma_f32_16x16x32_bf16(ah0, bl0, a0, 0, 0, 0);
            a1 = __builtin_amdgcn_mfma_f32_16x16x32_bf16(ah1, bl1, a1, 0, 0, 0);
            a0 = __builtin_amdgcn_mfma_f32_16x16x32_bf16(ah0, bh0, a0, 0, 0, 0);
            a1 = __builtin_amdgcn_mfma_f32_16x16x32_bf16(ah1, bh1, a1, 0, 0, 0);
#pragma unroll
            for (int reg = 0; reg < 4; ++reg) {
                float vv = a0[reg] + a1[reg];
                bool  lt = vv < m1[reg];
                float mx = fmaxf(vv, m1[reg]);       // top-2 identity:
                m2[reg] = fminf(m2[reg], mx);        //  m2' = min(m2, max(m1,vv))
                m1[reg] = fminf(m1[reg], vv);        //  m1' = min(m1, vv)
                i1[reg] = lt ? idx : i1[reg];
            }
        }
    }

    // ---- 16-lane butterfly finalize + flag decision ----
#pragma unroll
    for (int reg = 0; reg < 4; ++reg) {
        float a1v = m1[reg], a2v = m2[reg];
        int   ai  = i1[reg];
#pragma unroll
        for (int s = 1; s < 16; s <<= 1) {
            float o1 = __shfl_xor(a1v, s, 16);
            int   oi = __shfl_xor(ai, s, 16);
            float o2 = __shfl_xor(a2v, s, 16);
            merge2(a1v, ai, a2v, o1, oi, o2);
        }
        if (ln15 == 0) {
            int row = (w << 4) + (quad << 2) + reg;
            float znr = znrow[row];
            float W = 1.4e-4f * __builtin_sqrtf(znr * snm) + 1e-3f;  // sound 2x err bound
            biarr[row] = ai;
            if (a2v > a1v + W) {          // gap > W => approx argmin == exact argmin
                out_idx[n0 + row] = (float)ai;
            } else {
                int pos = atomicAdd(&nflag, 1);   // LDS atomic
                flaglist[pos] = row;
            }
        }
    }
    __syncthreads();

    // ---- exact fp32 rescue (one wave per flagged row; ~1% of rows) ----
    int nf = nflag;
    for (int f = w; f < nf; f += 4) {
        int r = flaglist[f];
        float zl = xbase[((size_t)lane << 12) + r];   // exact z[lane], L2-hot
        float d[8];
#pragma unroll
        for (int j = 0; j < 8; ++j) d[j] = 0.f;
        for (int c4 = 0; c4 < 16; ++c4) {
            float z0 = __shfl(zl, (c4 << 2) + 0, 64);
            float z1 = __shfl(zl, (c4 << 2) + 1, 64);
            float z2 = __shfl(zl, (c4 << 2) + 2, 64);
            float z3 = __shfl(zl, (c4 << 2) + 3, 64);
#pragma unroll
            for (int j = 0; j < 8; ++j) {
                float4_t e = *(const float4_t*)(embT32 + ((((lane << 3) + j) << 6) + (c4 << 2)));
                d[j] = fmaf(z0, e[0], d[j]);
                d[j] = fmaf(z1, e[1], d[j]);
                d[j] = fmaf(z2, e[2], d[j]);
                d[j] = fmaf(z3, e[3], d[j]);
            }
        }
        float znr = znrow[r];
        float best = 3.4e38f;
        int   bidx = 0;
#pragma unroll
        for (int j = 0; j < 8; ++j) {
            int k = (lane << 3) + j;
            float dist = (znr + sEn[k]) - 2.f * d[j];   // reference eval order
            if (dist < best) { best = dist; bidx = k; }
        }
#pragma unroll
        for (int off = 32; off > 0; off >>= 1) {
            float ov = __shfl_down(best, off, 64);
            int   oi = __shfl_down(bidx, off, 64);
            if (ov < best || (ov == best && oi < bidx)) { best = ov; bidx = oi; }
        }
        if (lane == 0) {
            biarr[r] = bidx;
            out_idx[n0 + r] = (float)bidx;
        }
    }
    __syncthreads();

    // ---- phase 2 (register-based): lane covers row = myrow, c = quad*8+j (+32) ----
    const int code  = biarr[myrow];
    const float* eb = embT32 + (code << 6) + (quad << 3);
    float4_t e0 = *(const float4_t*)(eb);          // c = quad*8 + 0..3
    float4_t e1 = *(const float4_t*)(eb + 4);      // c = quad*8 + 4..7
    float4_t e2 = *(const float4_t*)(eb + 32);     // c = 32 + quad*8 + 0..3
    float4_t e3 = *(const float4_t*)(eb + 36);     // c = 32 + quad*8 + 4..7
    float* qrow = out_q + ((size_t)b << 18) + hw0 + myrow;
    float sacc = 0.f;
#pragma unroll
    for (int j = 0; j < 4; ++j) {
        int c0 = (quad << 3) + j;
        int c1 = (quad << 3) + 4 + j;
        // chunk 0 (c < 32): frags ah0/al0
        float zA = bf2f((unsigned short)ah0[j])     + bf2f((unsigned short)al0[j]);
        float zB = bf2f((unsigned short)ah0[4 + j]) + bf2f((unsigned short)al0[4 + j]);
        float dA = e0[j] - zA, dB = e1[j] - zB;
        sacc += dA * dA + dB * dB;
        qrow[(size_t)c0 << 12] = e0[j];
        qrow[(size_t)c1 << 12] = e1[j];
        // chunk 1 (c >= 32): frags ah1/al1
        float zC = bf2f((unsigned short)ah1[j])     + bf2f((unsigned short)al1[j]);
        float zD = bf2f((unsigned short)ah1[4 + j]) + bf2f((unsigned short)al1[4 + j]);
        float dC = e2[j] - zC, dD = e3[j] - zD;
        sacc += dC * dC + dD * dD;
        qrow[(size_t)(32 + c0) << 12] = e2[j];
        qrow[(size_t)(32 + c1) << 12] = e3[j];
    }
#pragma unroll
    for (int off = 32; off > 0; off >>= 1)
        sacc += __shfl_down(sacc, off, 64);
    if (lane == 0) wsse[w] = sacc;
    __syncthreads();

    // ---- tail: regular SSE store + slotted relaxed hist atomics (no fence,
    //      no barrier after — ACK wait overlaps wave retirement) ----
    if (t == 0)
        ssepart[blockIdx.x] = (double)wsse[0] + (double)wsse[1]
                            + (double)wsse[2] + (double)wsse[3];
    if (t < ROWS_)
        __hip_atomic_fetch_add(&ghist8[((blockIdx.x & (NSLOT_ - 1)) << 9) + biarr[t]],
                               1, __ATOMIC_RELAXED, __HIP_MEMORY_SCOPE_AGENT);
}

// ---------------- finale: loss + perplexity (1 block) ----------------
__global__ __launch_bounds__(512) void vq_final(const int* __restrict__ ghist8,
                                                const double* __restrict__ ssepart,
                                                float* __restrict__ out_loss,
                                                float* __restrict__ out_perp) {
    __shared__ float  wsf[8];
    __shared__ double wsd[8];
    int t = threadIdx.x;
    int hsum = 0;
#pragma unroll
    for (int s8 = 0; s8 < NSLOT_; ++s8)
        hsum += ghist8[(s8 << 9) + t];    // coalesced over t
    float p = (float)hsum / (float)N_;
    float s = p * logf(p + 1e-10f);
    double d = ssepart[t] + ssepart[t + 512] + ssepart[t + 1024] + ssepart[t + 1536];
#pragma unroll
    for (int off = 32; off > 0; off >>= 1) {
        s += __shfl_down(s, off, 64);
        d += __shfl_down(d, off, 64);
    }
    if ((t & 63) == 0) { wsf[t >> 6] = s; wsd[t >> 6] = d; }
    __syncthreads();
    if (t == 0) {
        float  S = 0.f;
        double D = 0.0;
#pragma unroll
        for (int w = 0; w < 8; ++w) { S += wsf[w]; D += wsd[w]; }
        *out_perp = expf(-S);
        *out_loss = (float)(1.25 * D / (double)NC_);
    }
}

extern "C" void kernel_launch(void* const* d_in, const int* in_sizes, int n_in,
                              void* d_out, int out_size, void* d_ws, size_t ws_size,
                              hipStream_t stream) {
    const float* x   = (const float*)d_in[0];
    const float* emb = (const float*)d_in[1];

    float* out      = (float*)d_out;
    float* out_loss = out;
    float* out_q    = out + 1;
    float* out_perp = out + 1 + (size_t)N_ * C_;
    float* out_idx  = out + 2 + (size_t)N_ * C_;

    char* ws = (char*)d_ws;
    float*          snmax_p  = (float*)(ws + 56);
    float*          en       = (float*)(ws + 2112);
    float*          embT32   = (float*)(ws + 4160);
    unsigned short* fBhi     = (unsigned short*)(ws + 135232);
    unsigned short* fBlo     = (unsigned short*)(ws + 200768);
    int*            ghist8   = (int*)(ws + 266304);
    double*         ssepart  = (double*)(ws + 282688);

    vq_init<<<65, 512, 0, stream>>>(emb, snmax_p, en, embT32, fBhi, fBlo, ghist8);
    vq_argmin<<<NBLK_, 256, 0, stream>>>(x, en, embT32, fBhi, fBlo, snmax_p,
                                         out_q, out_idx, ghist8, ssepart);
    vq_final<<<1, 512, 0, stream>>>(ghist8, ssepart, out_loss, out_perp);
}

// Round 3
// 164.127 us; speedup vs baseline: 1.6370x; 1.0036x over previous
//
#include <hip/hip_runtime.h>

// VQ-VAE vector quantizer — R9.
// R8 post-mortem: argmin 98us with MFMA 10%/VALU 27%/HBM 7.5%/occ 20% => pure
// latency-bound. 32 K-loop iterations each expose ~250-300cy of L2 latency on
// the 4 B-tile loads (VGPR=76 left the compiler no room to pipeline; ~1.6
// blocks/CU resident gives no TLP cover). 8 blocks/CU x ~29Kcy = the 98us.
// R9: explicit register double-buffered B prefetch at whole-p granularity
// (2 sets x 8 short8 = 64 VGPR): compute(A,p) / load(A,p+2) / compute(B,p+1) /
// load(B,p+3). Each load covered by a full compute phase (12 MFMA in 4 indep
// chains + 2 top-2 updates ~300cy >= L2 latency). p=0/1 loads issued at kernel
// top; the single pre-loop barrier drains them for free. Math bit-identical
// to R8 (same per-chain MFMA order). Epilogue unchanged (R8-proven).

#define B_ 32
#define C_ 64
#define HW_ 4096
#define K_ 512
#define N_ (B_ * HW_)
#define NC_ ((long long)N_ * C_)
#define ROWS_ 64
#define NBLK_ (N_ / ROWS_)     // 2048
#define NSLOT_ 8

typedef __attribute__((ext_vector_type(8))) short short8;
typedef __attribute__((ext_vector_type(4))) float float4_t;

// ---- workspace layout (bytes) ----
// 56      float  snmax               4*max_k ||e_k||^2
// 2112    float  en[512]
// 4160    float  embT32[512*64]      exact fp32 emb, [code][c]
// 135232  ushort fBhi[512*64]        bf16 hi of (-2e), fragment-linear
// 200768  ushort fBlo[512*64]        bf16 lo of (-2e), fragment-linear
// 266304  int    ghist8[8*512]       slotted histogram (16 KB)
// 282688  double ssepart[2048]       (16 KB) -> end 299072

__device__ __forceinline__ unsigned short f2bf(float f) {
    unsigned u = __float_as_uint(f);
    u += 0x7fffu + ((u >> 16) & 1u);   // RNE
    return (unsigned short)(u >> 16);
}
__device__ __forceinline__ float bf2f(unsigned short h) {
    return __uint_as_float(((unsigned)h) << 16);
}
__device__ __forceinline__ void merge2(float& m1, int& i1, float& m2,
                                       float om1, int oi1, float om2) {
    if (om1 < m1) { m2 = fminf(m1, om2); m1 = om1; i1 = oi1; }
    else          { m2 = fminf(m2, om1); }
}

// ---------------- prologue ----------------
__global__ __launch_bounds__(512) void vq_init(const float* __restrict__ emb,
                                               float* __restrict__ snmax_p,
                                               float* __restrict__ en,
                                               float* __restrict__ embT32,
                                               unsigned short* __restrict__ fBhi,
                                               unsigned short* __restrict__ fBlo,
                                               int* __restrict__ ghist8) {
    __shared__ float smax[8];
    int k = threadIdx.x;                  // code 0..511
    if (blockIdx.x < 64) {
        int c = blockIdx.x;
        float e = emb[c * K_ + k];        // coalesced over k
        embT32[k * C_ + c] = e;
        float s = -2.0f * e;
        unsigned short hi = f2bf(s);
        unsigned short lo = f2bf(s - bf2f(hi));
        // fragment-linear: fb = [k>>5][(k>>4)&1][c>>5], then lane, then 8 k
        int kk   = c >> 5;
        int lane = (((c & 31) >> 3) << 4) + (k & 15);
        int fb   = ((k >> 5) << 2) + (((k >> 4) & 1) << 1) + kk;
        int off  = (fb << 9) + (lane << 3) + (c & 7);
        fBhi[off] = hi;
        fBlo[off] = lo;
    } else {
        // zero slotted histogram (re-done every graph replay)
#pragma unroll
        for (int s8 = 0; s8 < NSLOT_; ++s8) ghist8[(s8 << 9) + k] = 0;
        float s = 0.f;
#pragma unroll
        for (int c = 0; c < C_; ++c) {
            float e = emb[c * K_ + k];
            s += e * e;
        }
        en[k] = s;
        float m = s;
#pragma unroll
        for (int off = 32; off > 0; off >>= 1)
            m = fmaxf(m, __shfl_down(m, off, 64));
        if ((k & 63) == 0) smax[k >> 6] = m;
        __syncthreads();
        if (k == 0) {
            float mm = smax[0];
#pragma unroll
            for (int w2 = 1; w2 < 8; ++w2) mm = fmaxf(mm, smax[w2]);
            *snmax_p = 4.0f * mm;
        }
    }
}

// B-tile register set: per p, 8 x short8 (hi: h0,h1 ct0 / g0,g1 ct1; lo: l0,l1 / q0,q1)
#define LOAD_B(S, pp) do {                                                    \
    const unsigned short* hp_ = fBhi + (((pp) << 11) + (lane << 3));          \
    const unsigned short* lp_ = fBlo + (((pp) << 11) + (lane << 3));          \
    S##h0 = *(const short8*)(hp_);                                            \
    S##h1 = *(const short8*)(hp_ + 512);                                      \
    S##g0 = *(const short8*)(hp_ + 1024);                                     \
    S##g1 = *(const short8*)(hp_ + 1536);                                     \
    S##l0 = *(const short8*)(lp_);                                            \
    S##l1 = *(const short8*)(lp_ + 512);                                      \
    S##q0 = *(const short8*)(lp_ + 1024);                                     \
    S##q1 = *(const short8*)(lp_ + 1536);                                     \
} while (0)

#define COMP_P(S, pp) do {                                                    \
    const int cb_ = ((pp) << 5) + ln15;                                       \
    float env0_ = sEn[cb_];                                                   \
    float env1_ = sEn[cb_ + 16];                                              \
    float4_t a0 = {env0_, env0_, env0_, env0_};                               \
    float4_t a1 = {0.f, 0.f, 0.f, 0.f};                                       \
    float4_t b0 = {env1_, env1_, env1_, env1_};                               \
    float4_t b1 = {0.f, 0.f, 0.f, 0.f};                                       \
    a0 = __builtin_amdgcn_mfma_f32_16x16x32_bf16(al0, S##h0, a0, 0, 0, 0);    \
    a1 = __builtin_amdgcn_mfma_f32_16x16x32_bf16(al1, S##h1, a1, 0, 0, 0);    \
    b0 = __builtin_amdgcn_mfma_f32_16x16x32_bf16(al0, S##g0, b0, 0, 0, 0);    \
    b1 = __builtin_amdgcn_mfma_f32_16x16x32_bf16(al1, S##g1, b1, 0, 0, 0);    \
    a0 = __builtin_amdgcn_mfma_f32_16x16x32_bf16(ah0, S##l0, a0, 0, 0, 0);    \
    a1 = __builtin_amdgcn_mfma_f32_16x16x32_bf16(ah1, S##l1, a1, 0, 0, 0);    \
    b0 = __builtin_amdgcn_mfma_f32_16x16x32_bf16(ah0, S##q0, b0, 0, 0, 0);    \
    b1 = __builtin_amdgcn_mfma_f32_16x16x32_bf16(ah1, S##q1, b1, 0, 0, 0);    \
    a0 = __builtin_amdgcn_mfma_f32_16x16x32_bf16(ah0, S##h0, a0, 0, 0, 0);    \
    a1 = __builtin_amdgcn_mfma_f32_16x16x32_bf16(ah1, S##h1, a1, 0, 0, 0);    \
    b0 = __builtin_amdgcn_mfma_f32_16x16x32_bf16(ah0, S##g0, b0, 0, 0, 0);    \
    b1 = __builtin_amdgcn_mfma_f32_16x16x32_bf16(ah1, S##g1, b1, 0, 0, 0);    \
    _Pragma("unroll")                                                         \
    for (int reg = 0; reg < 4; ++reg) {                                       \
        float vv = a0[reg] + a1[reg];                                         \
        bool  lt = vv < m1[reg];                                              \
        float mx = fmaxf(vv, m1[reg]);                                        \
        m2[reg] = fminf(m2[reg], mx);                                         \
        m1[reg] = fminf(m1[reg], vv);                                         \
        i1[reg] = lt ? cb_ : i1[reg];                                         \
    }                                                                         \
    _Pragma("unroll")                                                         \
    for (int reg = 0; reg < 4; ++reg) {                                       \
        float vv = b0[reg] + b1[reg];                                         \
        bool  lt = vv < m1[reg];                                              \
        float mx = fmaxf(vv, m1[reg]);                                        \
        m2[reg] = fminf(m2[reg], mx);                                         \
        m1[reg] = fminf(m1[reg], vv);                                         \
        i1[reg] = lt ? (cb_ + 16) : i1[reg];                                  \
    }                                                                         \
} while (0)

// ---------------- main kernel: argmin + q + SSE + slotted hist ----------------
__global__ __launch_bounds__(256) void vq_argmin(const float* __restrict__ x,
                                                 const float* __restrict__ en_g,
                                                 const float* __restrict__ embT32,
                                                 const unsigned short* __restrict__ fBhi,
                                                 const unsigned short* __restrict__ fBlo,
                                                 const float* __restrict__ snmax_p,
                                                 float* __restrict__ out_q,
                                                 float* __restrict__ out_idx,
                                                 int* __restrict__ ghist8,
                                                 double* __restrict__ ssepart) {
    __shared__ float sEn[K_];                    // 2 KB
    __shared__ float znrow[ROWS_];
    __shared__ int   biarr[ROWS_];
    __shared__ int   flaglist[ROWS_];
    __shared__ float wsse[4];
    __shared__ int   nflag;

    const int t    = threadIdx.x;
    const int lane = t & 63;
    const int w    = t >> 6;             // wave owns row-tile w (rows w*16..+15)
    const int ln15 = lane & 15;
    const int quad = lane >> 4;
    const int n0   = blockIdx.x * ROWS_;
    const int b    = n0 >> 12;
    const int hw0  = n0 & 4095;
    const float* xbase = x + ((size_t)b << 18) + hw0;
    const int myrow = (w << 4) + ln15;

    if (t == 0) nflag = 0;
    sEn[t]       = en_g[t];
    sEn[256 + t] = en_g[256 + t];

    // ---- direct A-fragment load: lane holds row=myrow, c = quad*8+j (+32) ----
    float v0[8], v1[8];
#pragma unroll
    for (int j = 0; j < 8; ++j) {
        v0[j] = xbase[((size_t)((quad << 3) + j) << 12) + myrow];
        v1[j] = xbase[((size_t)(32 + (quad << 3) + j) << 12) + myrow];
    }

    // ---- issue B prefetch for p=0,1 NOW (L2 latency hides under conversions;
    //      the pre-loop barrier's vmcnt(0) drain lands after they've arrived) ----
    short8 A_h0, A_h1, A_g0, A_g1, A_l0, A_l1, A_q0, A_q1;
    short8 B_h0, B_h1, B_g0, B_g1, B_l0, B_l1, B_q0, B_q1;
    LOAD_B(A_, 0);
    LOAD_B(B_, 1);

    short8 ah0, al0, ah1, al1;
    float znacc = 0.f;
#pragma unroll
    for (int j = 0; j < 8; ++j) {
        unsigned short h0 = f2bf(v0[j]);
        ah0[j] = (short)h0;
        al0[j] = (short)f2bf(v0[j] - bf2f(h0));
        unsigned short h1 = f2bf(v1[j]);
        ah1[j] = (short)h1;
        al1[j] = (short)f2bf(v1[j] - bf2f(h1));
        znacc += v0[j] * v0[j] + v1[j] * v1[j];
    }
    // full ||z_row||^2: reduce over the 4 quads holding the same row
    znacc += __shfl_xor(znacc, 16, 64);
    znacc += __shfl_xor(znacc, 32, 64);
    if (quad == 0) znrow[myrow] = znacc;
    __syncthreads();     // sEn + znrow + nflag visible

    const float snm = *snmax_p;

    // ---- stream 512 codes: 16 p-tiles, register double-buffered prefetch ----
    float m1[4], m2[4];
    int   i1[4];
#pragma unroll
    for (int reg = 0; reg < 4; ++reg) {
        m1[reg] = 3.4e38f; m2[reg] = 3.4e38f; i1[reg] = 0;
    }

    for (int p = 0; p < 16; p += 2) {
        COMP_P(A_, p);                   // waits on A_ loads (in flight 1 phase)
        LOAD_B(A_, (p + 2) & 15);        // wrap: tail loads are harmless re-reads
        COMP_P(B_, p + 1);
        LOAD_B(B_, (p + 3) & 15);
    }

    // ---- 16-lane butterfly finalize + flag decision ----
#pragma unroll
    for (int reg = 0; reg < 4; ++reg) {
        float a1v = m1[reg], a2v = m2[reg];
        int   ai  = i1[reg];
#pragma unroll
        for (int s = 1; s < 16; s <<= 1) {
            float o1 = __shfl_xor(a1v, s, 16);
            int   oi = __shfl_xor(ai, s, 16);
            float o2 = __shfl_xor(a2v, s, 16);
            merge2(a1v, ai, a2v, o1, oi, o2);
        }
        if (ln15 == 0) {
            int row = (w << 4) + (quad << 2) + reg;
            float znr = znrow[row];
            float W = 1.4e-4f * __builtin_sqrtf(znr * snm) + 1e-3f;  // sound 2x err bound
            biarr[row] = ai;
            if (a2v > a1v + W) {          // gap > W => approx argmin == exact argmin
                out_idx[n0 + row] = (float)ai;
            } else {
                int pos = atomicAdd(&nflag, 1);   // LDS atomic
                flaglist[pos] = row;
            }
        }
    }
    __syncthreads();

    // ---- exact fp32 rescue (one wave per flagged row; ~1% of rows) ----
    int nf = nflag;
    for (int f = w; f < nf; f += 4) {
        int r = flaglist[f];
        float zl = xbase[((size_t)lane << 12) + r];   // exact z[lane], L2-hot
        float d[8];
#pragma unroll
        for (int j = 0; j < 8; ++j) d[j] = 0.f;
        for (int c4 = 0; c4 < 16; ++c4) {
            float z0 = __shfl(zl, (c4 << 2) + 0, 64);
            float z1 = __shfl(zl, (c4 << 2) + 1, 64);
            float z2 = __shfl(zl, (c4 << 2) + 2, 64);
            float z3 = __shfl(zl, (c4 << 2) + 3, 64);
#pragma unroll
            for (int j = 0; j < 8; ++j) {
                float4_t e = *(const float4_t*)(embT32 + ((((lane << 3) + j) << 6) + (c4 << 2)));
                d[j] = fmaf(z0, e[0], d[j]);
                d[j] = fmaf(z1, e[1], d[j]);
                d[j] = fmaf(z2, e[2], d[j]);
                d[j] = fmaf(z3, e[3], d[j]);
            }
        }
        float znr = znrow[r];
        float best = 3.4e38f;
        int   bidx = 0;
#pragma unroll
        for (int j = 0; j < 8; ++j) {
            int k = (lane << 3) + j;
            float dist = (znr + sEn[k]) - 2.f * d[j];   // reference eval order
            if (dist < best) { best = dist; bidx = k; }
        }
#pragma unroll
        for (int off = 32; off > 0; off >>= 1) {
            float ov = __shfl_down(best, off, 64);
            int   oi = __shfl_down(bidx, off, 64);
            if (ov < best || (ov == best && oi < bidx)) { best = ov; bidx = oi; }
        }
        if (lane == 0) {
            biarr[r] = bidx;
            out_idx[n0 + r] = (float)bidx;
        }
    }
    __syncthreads();

    // ---- phase 2 (register-based): lane covers row = myrow, c = quad*8+j (+32) ----
    const int code  = biarr[myrow];
    const float* eb = embT32 + (code << 6) + (quad << 3);
    float4_t e0 = *(const float4_t*)(eb);          // c = quad*8 + 0..3
    float4_t e1 = *(const float4_t*)(eb + 4);      // c = quad*8 + 4..7
    float4_t e2 = *(const float4_t*)(eb + 32);     // c = 32 + quad*8 + 0..3
    float4_t e3 = *(const float4_t*)(eb + 36);     // c = 32 + quad*8 + 4..7
    float* qrow = out_q + ((size_t)b << 18) + hw0 + myrow;
    float sacc = 0.f;
#pragma unroll
    for (int j = 0; j < 4; ++j) {
        int c0 = (quad << 3) + j;
        int c1 = (quad << 3) + 4 + j;
        // chunk 0 (c < 32): frags ah0/al0
        float zA = bf2f((unsigned short)ah0[j])     + bf2f((unsigned short)al0[j]);
        float zB = bf2f((unsigned short)ah0[4 + j]) + bf2f((unsigned short)al0[4 + j]);
        float dA = e0[j] - zA, dB = e1[j] - zB;
        sacc += dA * dA + dB * dB;
        qrow[(size_t)c0 << 12] = e0[j];
        qrow[(size_t)c1 << 12] = e1[j];
        // chunk 1 (c >= 32): frags ah1/al1
        float zC = bf2f((unsigned short)ah1[j])     + bf2f((unsigned short)al1[j]);
        float zD = bf2f((unsigned short)ah1[4 + j]) + bf2f((unsigned short)al1[4 + j]);
        float dC = e2[j] - zC, dD = e3[j] - zD;
        sacc += dC * dC + dD * dD;
        qrow[(size_t)(32 + c0) << 12] = e2[j];
        qrow[(size_t)(32 + c1) << 12] = e3[j];
    }
#pragma unroll
    for (int off = 32; off > 0; off >>= 1)
        sacc += __shfl_down(sacc, off, 64);
    if (lane == 0) wsse[w] = sacc;
    __syncthreads();

    // ---- tail: regular SSE store + slotted relaxed hist atomics (no fence,
    //      no barrier after — ACK wait overlaps wave retirement) ----
    if (t == 0)
        ssepart[blockIdx.x] = (double)wsse[0] + (double)wsse[1]
                            + (double)wsse[2] + (double)wsse[3];
    if (t < ROWS_)
        __hip_atomic_fetch_add(&ghist8[((blockIdx.x & (NSLOT_ - 1)) << 9) + biarr[t]],
                               1, __ATOMIC_RELAXED, __HIP_MEMORY_SCOPE_AGENT);
}

// ---------------- finale: loss + perplexity (1 block) ----------------
__global__ __launch_bounds__(512) void vq_final(const int* __restrict__ ghist8,
                                                const double* __restrict__ ssepart,
                                                float* __restrict__ out_loss,
                                                float* __restrict__ out_perp) {
    __shared__ float  wsf[8];
    __shared__ double wsd[8];
    int t = threadIdx.x;
    int hsum = 0;
#pragma unroll
    for (int s8 = 0; s8 < NSLOT_; ++s8)
        hsum += ghist8[(s8 << 9) + t];    // coalesced over t
    float p = (float)hsum / (float)N_;
    float s = p * logf(p + 1e-10f);
    double d = ssepart[t] + ssepart[t + 512] + ssepart[t + 1024] + ssepart[t + 1536];
#pragma unroll
    for (int off = 32; off > 0; off >>= 1) {
        s += __shfl_down(s, off, 64);
        d += __shfl_down(d, off, 64);
    }
    if ((t & 63) == 0) { wsf[t >> 6] = s; wsd[t >> 6] = d; }
    __syncthreads();
    if (t == 0) {
        float  S = 0.f;
        double D = 0.0;
#pragma unroll
        for (int w = 0; w < 8; ++w) { S += wsf[w]; D += wsd[w]; }
        *out_perp = expf(-S);
        *out_loss = (float)(1.25 * D / (double)NC_);
    }
}

extern "C" void kernel_launch(void* const* d_in, const int* in_sizes, int n_in,
                              void* d_out, int out_size, void* d_ws, size_t ws_size,
                              hipStream_t stream) {
    const float* x   = (const float*)d_in[0];
    const float* emb = (const float*)d_in[1];

    float* out      = (float*)d_out;
    float* out_loss = out;
    float* out_q    = out + 1;
    float* out_perp = out + 1 + (size_t)N_ * C_;
    float* out_idx  = out + 2 + (size_t)N_ * C_;

    char* ws = (char*)d_ws;
    float*          snmax_p  = (float*)(ws + 56);
    float*          en       = (float*)(ws + 2112);
    float*          embT32   = (float*)(ws + 4160);
    unsigned short* fBhi     = (unsigned short*)(ws + 135232);
    unsigned short* fBlo     = (unsigned short*)(ws + 200768);
    int*            ghist8   = (int*)(ws + 266304);
    double*         ssepart  = (double*)(ws + 282688);

    vq_init<<<65, 512, 0, stream>>>(emb, snmax_p, en, embT32, fBhi, fBlo, ghist8);
    vq_argmin<<<NBLK_, 256, 0, stream>>>(x, en, embT32, fBhi, fBlo, snmax_p,
                                         out_q, out_idx, ghist8, ssepart);
    vq_final<<<1, 512, 0, stream>>>(ghist8, ssepart, out_loss, out_perp);
}